// Round 8
// baseline (45000.635 us; speedup 1.0000x reference)
//
#include <hip/hip_runtime.h>

#define Bn 128
#define Tn 1024
#define INn 256
#define Hn 512
#define NB 256   // persistent blocks (1 per CU), 1024 threads each

typedef short bf16x8 __attribute__((ext_vector_type(8)));
typedef float f32x4 __attribute__((ext_vector_type(4)));

// ---- ws layout (bytes) ----
#define WHI_OFF  0u
#define WLO_OFF  11534336u
#define BIAS_OFF 23068672u
#define HH_OFF   23093248u   // bf16 [3][2][128][512]
#define HL_OFF   24666112u   // bf16 [3][2][128][512]
#define H3F_OFF  26238976u   // f32  [128][512]
#define CNT_OFF  26501120u   // 8KB barrier area

__device__ __forceinline__ float sigm(float x) { return 1.0f / (1.0f + __expf(-x)); }
__device__ __forceinline__ unsigned short bf_hi(float x) {
  unsigned u = __builtin_bit_cast(unsigned, x);
  return (unsigned short)(u >> 16);
}
__device__ __forceinline__ float bf_f(unsigned short h) {
  unsigned u = ((unsigned)h) << 16;
  return __builtin_bit_cast(float, u);
}

// Pack fp32 weights into MFMA-fragment-ordered bf16 hi/lo arrays.
// dst elem offset = layer_base + (((jt*2+ns)*NCH + kc)*64 + lane)*8
// col n = ns*16+(lane&15) -> gate row r = (n>>3)*512 + jt*8 + (n&7),
// k0 = kc*32 + (lane>>4)*8 over concat [x ; h]  (same (lane,e)->k map as A-frags).
__global__ void pack_weights(const float* __restrict__ wih1, const float* __restrict__ whh1,
                             const float* __restrict__ wih2, const float* __restrict__ whh2,
                             const float* __restrict__ wih3, const float* __restrict__ whh3,
                             unsigned short* __restrict__ whi, unsigned short* __restrict__ wlo) {
  int gid = blockIdx.x * 256 + threadIdx.x;
  int rem, NCH, kih; size_t base; const float *wih, *whh;
  if (gid < 196608)      { rem = gid;          base = 0;       NCH = 24; kih = 256; wih = wih1; whh = whh1; }
  else if (gid < 458752) { rem = gid - 196608; base = 1572864; NCH = 32; kih = 512; wih = wih2; whh = whh2; }
  else if (gid < 720896) { rem = gid - 458752; base = 3670016; NCH = 32; kih = 512; wih = wih3; whh = whh3; }
  else return;
  const int lane = rem & 63; rem >>= 6;
  const int kc = rem % NCH; rem /= NCH;
  const int ns = rem & 1;
  const int jt = rem >> 1;
  const int n = ns * 16 + (lane & 15);
  const int g = n >> 3, jl = n & 7;
  const int r = g * 512 + jt * 8 + jl;
  const int k0 = kc * 32 + (lane >> 4) * 8;
  const float* src = (k0 < kih) ? (wih + (size_t)r * kih + k0)
                                : (whh + (size_t)r * 512 + (k0 - kih));
  size_t dst = base + ((((size_t)jt * 2 + ns) * NCH + kc) * 64 + lane) * 8;
#pragma unroll
  for (int e = 0; e < 8; ++e) {
    float w = src[e];
    unsigned short h = bf_hi(w);
    whi[dst + e] = h;
    wlo[dst + e] = bf_hi(w - bf_f(h));
  }
}

__global__ void pack_bias(const float* __restrict__ bi1, const float* __restrict__ bh1,
                          const float* __restrict__ bi2, const float* __restrict__ bh2,
                          const float* __restrict__ bi3, const float* __restrict__ bh3,
                          float* __restrict__ bias) {
  int gid = blockIdx.x * 256 + threadIdx.x;
  if (gid >= 6144) return;
  int l = gid >> 11, r = gid & 2047;
  const float* bi = (l == 0) ? bi1 : (l == 1) ? bi2 : bi3;
  const float* bh = (l == 0) ? bh1 : (l == 1) ? bh2 : bh3;
  bias[gid] = bi[r] + bh[r];
}

// Two-level flag barrier (r4-proven). bar words: [x*32] per-XCD ctr,
// [256] root, [288] epoch. Monotonic idx. RELAXED polls + final ACQUIRE;
// leader's ACQ_REL RMW / ACQUIRE load emit the wbl2/inv that make the
// phase's h stores (already in L2 after __syncthreads) globally visible.
__device__ __forceinline__ void gridbar(unsigned* bar, unsigned idx, int xcd) {
  __syncthreads();
  if (threadIdx.x == 0) {
    unsigned* xc   = bar + xcd * 32;
    unsigned* root = bar + 256;
    unsigned* ep   = bar + 288;
    unsigned o = __hip_atomic_fetch_add(xc, 1u, __ATOMIC_ACQ_REL, __HIP_MEMORY_SCOPE_AGENT);
    if (o == idx * 32u - 1u) {
      unsigned r = __hip_atomic_fetch_add(root, 1u, __ATOMIC_ACQ_REL, __HIP_MEMORY_SCOPE_AGENT);
      if (r == idx * 8u - 1u)
        __hip_atomic_store(ep, idx, __ATOMIC_RELEASE, __HIP_MEMORY_SCOPE_AGENT);
    }
    while (__hip_atomic_load(ep, __ATOMIC_RELAXED, __HIP_MEMORY_SCOPE_AGENT) < idx)
      __builtin_amdgcn_s_sleep(1);
    (void)__hip_atomic_load(ep, __ATOMIC_ACQUIRE, __HIP_MEMORY_SCOPE_AGENT);
  }
  __syncthreads();
}

// Persistent fused LSTM: 256 blocks x 1024 threads (16 waves = 4/SIMD).
// Block = (b-tile 32, j-tile 8); layer l at t = p - l (3-stage pipeline).
// Wave w: bsub=w&1 (16 b-rows), nsub=(w>>1)&1 (16 gate-cols), kq=w>>2 (K quarter).
// A = 2-split bf16 (hi/lo), B = 2-split; 4 MFMAs (HH+LH+HL+LL).
// Cell state c lives in registers (tid<256). One grid barrier per phase.
__global__ __launch_bounds__(1024, 4) void lstm_persist(
    const float* __restrict__ embed,
    const unsigned short* __restrict__ whi,
    const unsigned short* __restrict__ wlo,
    const float* __restrict__ bias,
    unsigned short* __restrict__ hh,
    unsigned short* __restrict__ hl,
    float* __restrict__ h3f,
    unsigned* __restrict__ bar)
{
  const int bid = blockIdx.x;
  const int xcd = bid & 7;
  const int idx = bid >> 3;           // 0..31 within XCD
  const int jt  = xcd * 8 + (idx & 7);
  const int bt  = idx >> 3;           // 0..3
  const int j0  = jt * 8;
  const int b0  = bt * 32;
  const int tid = (int)threadIdx.x;
  const int lane = tid & 63;
  const int w = tid >> 6;             // 0..15
  const int bsub = w & 1, nsub = (w >> 1) & 1, kq = w >> 2;   // kq 0..3

  __shared__ float pre[2][4][32][36];   // [parity][kq][brow][gatecol]
  __shared__ float sbias[3][32];

  if (tid < 96) {
    int l = tid >> 5, n = tid & 31;
    sbias[l][n] = bias[l * 2048 + (n >> 3) * 512 + j0 + (n & 7)];
  }
  // zero h state (ws poisoned; deterministic per launch)
  for (int i = bid * 1024 + tid; i < 3 * 2 * Bn * Hn; i += NB * 1024) { hh[i] = 0; hl[i] = 0; }

  float c0 = 0.f, c1 = 0.f, c2 = 0.f;   // cell state for (b0+bloc, j0+jl), tid<256
  unsigned bidx = 1;
  gridbar(bar, bidx++, xcd);

  const int arow = b0 + bsub * 16 + (lane & 15);   // A-frag b row
  const int kgrp = (lane >> 4) * 8;                // k-offset in 32-chunk
  const int bloc = (tid >> 3) & 31, jl = tid & 7;  // cell-update mapping (tid<256)

  for (int p = 0; p <= 1024; ++p) {
    const int rp = (p + 1) & 1, wp = p & 1;

#pragma unroll
    for (int l = 0; l < 3; ++l) {
      const int t = p - l;
      if (t >= 0 && t <= 1022) {
        const int NCH = (l == 0) ? 24 : 32;
        const int quarter = NCH >> 2;                // 6 or 8
        const size_t wbase = (l == 0) ? 0u : ((l == 1) ? 1572864u : 3670016u);
        const unsigned short* wh = whi + wbase + ((size_t)(jt * 2 + nsub) * NCH) * 512 + lane * 8;
        const unsigned short* wl = wlo + wbase + ((size_t)(jt * 2 + nsub) * NCH) * 512 + lane * 8;

        f32x4 accA = {0.f,0.f,0.f,0.f}, accB = {0.f,0.f,0.f,0.f};
        const int kc0 = kq * quarter;

#pragma unroll
        for (int i = 0; i < 8; ++i) {
          if (i >= quarter) break;                   // compile-time per l
          const int kc = kc0 + i;
          const int k0 = kc * 32 + kgrp;
          bf16x8 aH, aL;
          if (l == 0 && k0 < 256) {                  // embed fp32 -> 2-split in-register
            const float* s = embed + ((size_t)arow * Tn + t) * INn + k0;
            const f32x4 x0 = *reinterpret_cast<const f32x4*>(s);
            const f32x4 x1 = *reinterpret_cast<const f32x4*>(s + 4);
            float xs[8] = {x0.x, x0.y, x0.z, x0.w, x1.x, x1.y, x1.z, x1.w};
#pragma unroll
            for (int e = 0; e < 8; ++e) {
              unsigned short h1 = bf_hi(xs[e]);
              aH[e] = (short)h1;
              aL[e] = (short)bf_hi(xs[e] - bf_f(h1));
            }
          } else {
            int srcl, off;
            if (l == 0)           { srcl = 0;     off = k0 - 256; }
            else if (k0 < 512)    { srcl = l - 1; off = k0;       }
            else                  { srcl = l;     off = k0 - 512; }
            const size_t ho = ((size_t)(srcl * 2 + rp) * Bn + arow) * Hn + off;
            aH = *reinterpret_cast<const bf16x8*>(hh + ho);
            aL = *reinterpret_cast<const bf16x8*>(hl + ho);
          }
          const bf16x8 bH = *reinterpret_cast<const bf16x8*>(wh + (size_t)kc * 512);
          const bf16x8 bL = *reinterpret_cast<const bf16x8*>(wl + (size_t)kc * 512);
          accA = __builtin_amdgcn_mfma_f32_16x16x32_bf16(aH, bH, accA, 0, 0, 0);
          accA = __builtin_amdgcn_mfma_f32_16x16x32_bf16(aL, bH, accA, 0, 0, 0);
          accB = __builtin_amdgcn_mfma_f32_16x16x32_bf16(aH, bL, accB, 0, 0, 0);
          accB = __builtin_amdgcn_mfma_f32_16x16x32_bf16(aL, bL, accB, 0, 0, 0);
        }

        const int pb = l & 1;  // l0/l2 share plane 0: separated by l1's __syncthreads
        {
          const int prow = bsub * 16 + ((lane >> 4) << 2);
          const int pc = nsub * 16 + (lane & 15);
#pragma unroll
          for (int r = 0; r < 4; ++r)
            pre[pb][kq][prow + r][pc] = accA[r] + accB[r];
        }
        __syncthreads();
        if (tid < 256) {
          float g0 = sbias[l][jl],      g1 = sbias[l][8 + jl];
          float g2 = sbias[l][16 + jl], g3 = sbias[l][24 + jl];
#pragma unroll
          for (int q = 0; q < 4; ++q) {
            g0 += pre[pb][q][bloc][jl];
            g1 += pre[pb][q][bloc][8 + jl];
            g2 += pre[pb][q][bloc][16 + jl];
            g3 += pre[pb][q][bloc][24 + jl];
          }
          const float ig = sigm(g0), fg = sigm(g1), gg = tanhf(g2), og = sigm(g3);
          float& c = (l == 0) ? c0 : ((l == 1) ? c1 : c2);
          c = fg * c + ig * gg;
          const float hv = og * tanhf(c);
          const unsigned short h1 = bf_hi(hv);
          const size_t ho = ((size_t)(l * 2 + wp) * Bn + (b0 + bloc)) * Hn + (j0 + jl);
          hh[ho] = h1;
          hl[ho] = bf_hi(hv - bf_f(h1));
          if (l == 2 && t == 1022)
            h3f[(size_t)(b0 + bloc) * Hn + (j0 + jl)] = hv;
        }
      }
    }
    gridbar(bar, bidx++, xcd);
  }
}

// FC epilogue: out2[b][o] = h3_final[b,:] . fc_w[o,:] + fc_b[o]
__global__ void fc_kernel(const float* __restrict__ h3f, const float* __restrict__ fcw,
                          const float* __restrict__ fcb, float* __restrict__ out) {
  const int gid = blockIdx.x * 256 + (int)threadIdx.x;
  if (gid >= Bn * INn) return;
  const int b = gid >> 8, o = gid & 255;
  const float* hr = h3f + (size_t)b * Hn;
  const float* wr = fcw + (size_t)o * Hn;
  float acc = fcb[o];
#pragma unroll 4
  for (int k = 0; k < Hn; k += 4) {
    const float4 hv = *reinterpret_cast<const float4*>(hr + k);
    const float4 wv = *reinterpret_cast<const float4*>(wr + k);
    acc = fmaf(hv.x, wv.x, acc); acc = fmaf(hv.y, wv.y, acc);
    acc = fmaf(hv.z, wv.z, acc); acc = fmaf(hv.w, wv.w, acc);
  }
  out[(size_t)Bn * Tn * INn + gid] = acc;
}

extern "C" void kernel_launch(void* const* d_in, const int* in_sizes, int n_in,
                              void* d_out, int out_size, void* d_ws, size_t ws_size,
                              hipStream_t stream) {
  const float* embed = (const float*)d_in[0];
  const float* wih1  = (const float*)d_in[1];
  const float* whh1  = (const float*)d_in[2];
  const float* bih1  = (const float*)d_in[3];
  const float* bhh1  = (const float*)d_in[4];
  const float* wih2  = (const float*)d_in[5];
  const float* whh2  = (const float*)d_in[6];
  const float* bih2  = (const float*)d_in[7];
  const float* bhh2  = (const float*)d_in[8];
  const float* wih3  = (const float*)d_in[9];
  const float* whh3  = (const float*)d_in[10];
  const float* bih3  = (const float*)d_in[11];
  const float* bhh3  = (const float*)d_in[12];
  const float* fcw   = (const float*)d_in[13];
  const float* fcb   = (const float*)d_in[14];
  float* outp = (float*)d_out;

  char* ws = (char*)d_ws;
  unsigned short* whi = (unsigned short*)(ws + WHI_OFF);
  unsigned short* wlo = (unsigned short*)(ws + WLO_OFF);
  float* bias         = (float*)(ws + BIAS_OFF);
  unsigned short* hh  = (unsigned short*)(ws + HH_OFF);
  unsigned short* hl  = (unsigned short*)(ws + HL_OFF);
  float* h3f          = (float*)(ws + H3F_OFF);
  unsigned* bar       = (unsigned*)(ws + CNT_OFF);

  // Output 0: embed passthrough (128 MB d2d)
  hipMemcpyAsync(d_out, d_in[0], (size_t)Bn * Tn * INn * sizeof(float),
                 hipMemcpyDeviceToDevice, stream);
  // barrier counters must start at 0 every launch
  hipMemsetAsync(bar, 0, 8192, stream);

  pack_weights<<<2816, 256, 0, stream>>>(wih1, whh1, wih2, whh2, wih3, whh3, whi, wlo);
  pack_bias<<<24, 256, 0, stream>>>(bih1, bhh1, bih2, bhh2, bih3, bhh3, bias);

  void* args[] = { (void*)&embed, (void*)&whi, (void*)&wlo, (void*)&bias,
                   (void*)&hh, (void*)&hl, (void*)&h3f, (void*)&bar };
  dim3 grid(NB), block(1024);
  hipLaunchCooperativeKernel((const void*)lstm_persist, grid, block, args, 0, stream);

  fc_kernel<<<128, 256, 0, stream>>>(h3f, fcw, fcb, outp);
}

// Round 9
// 33022.897 us; speedup vs baseline: 1.3627x; 1.3627x over previous
//
#include <hip/hip_runtime.h>

#define Bn 128
#define Tn 1024
#define INn 256
#define Hn 512
#define NB 256   // persistent blocks (1 per CU), 1024 threads each

typedef short bf16x8 __attribute__((ext_vector_type(8)));
typedef float f32x4 __attribute__((ext_vector_type(4)));

// ---- ws layout (bytes) ----
#define WHI_OFF  0u
#define WLO_OFF  11534336u
#define BIAS_OFF 23068672u
#define HH_OFF   23093248u   // bf16 [3][2][128][512]
#define HL_OFF   24666112u   // bf16 [3][2][128][512]
#define H3F_OFF  26238976u   // f32  [128][512]
#define CNT_OFF  26501120u   // 8KB barrier area

__device__ __forceinline__ float sigm(float x) { return 1.0f / (1.0f + __expf(-x)); }
__device__ __forceinline__ unsigned short bf_hi(float x) {
  unsigned u = __builtin_bit_cast(unsigned, x);
  return (unsigned short)(u >> 16);
}
__device__ __forceinline__ float bf_f(unsigned short h) {
  unsigned u = ((unsigned)h) << 16;
  return __builtin_bit_cast(float, u);
}

// System-scope (sc0 sc1: bypass L1+L2, served at MALL) 16B load as 2x8B
// relaxed atomic loads -- coherent across XCDs with NO cache invalidation.
struct ull2 { unsigned long long x, y; };
__device__ __forceinline__ bf16x8 ld16sys(const unsigned short* p) {
  ull2 t;
  t.x = __hip_atomic_load((const unsigned long long*)p,     __ATOMIC_RELAXED, __HIP_MEMORY_SCOPE_SYSTEM);
  t.y = __hip_atomic_load((const unsigned long long*)p + 1, __ATOMIC_RELAXED, __HIP_MEMORY_SCOPE_SYSTEM);
  return __builtin_bit_cast(bf16x8, t);
}
__device__ __forceinline__ void st2sys(unsigned short* p, unsigned short v) {
  __hip_atomic_store(p, v, __ATOMIC_RELAXED, __HIP_MEMORY_SCOPE_SYSTEM);
}

// Pack fp32 weights into MFMA-fragment-ordered bf16 hi/lo arrays.
// dst elem offset = layer_base + (((jt*2+ns)*NCH + kc)*64 + lane)*8
// col n = ns*16+(lane&15) -> gate row r = (n>>3)*512 + jt*8 + (n&7),
// k0 = kc*32 + (lane>>4)*8 over concat [x ; h]  (same (lane,e)->k map as A-frags).
__global__ void pack_weights(const float* __restrict__ wih1, const float* __restrict__ whh1,
                             const float* __restrict__ wih2, const float* __restrict__ whh2,
                             const float* __restrict__ wih3, const float* __restrict__ whh3,
                             unsigned short* __restrict__ whi, unsigned short* __restrict__ wlo) {
  int gid = blockIdx.x * 256 + threadIdx.x;
  int rem, NCH, kih; size_t base; const float *wih, *whh;
  if (gid < 196608)      { rem = gid;          base = 0;       NCH = 24; kih = 256; wih = wih1; whh = whh1; }
  else if (gid < 458752) { rem = gid - 196608; base = 1572864; NCH = 32; kih = 512; wih = wih2; whh = whh2; }
  else if (gid < 720896) { rem = gid - 458752; base = 3670016; NCH = 32; kih = 512; wih = wih3; whh = whh3; }
  else return;
  const int lane = rem & 63; rem >>= 6;
  const int kc = rem % NCH; rem /= NCH;
  const int ns = rem & 1;
  const int jt = rem >> 1;
  const int n = ns * 16 + (lane & 15);
  const int g = n >> 3, jl = n & 7;
  const int r = g * 512 + jt * 8 + jl;
  const int k0 = kc * 32 + (lane >> 4) * 8;
  const float* src = (k0 < kih) ? (wih + (size_t)r * kih + k0)
                                : (whh + (size_t)r * 512 + (k0 - kih));
  size_t dst = base + ((((size_t)jt * 2 + ns) * NCH + kc) * 64 + lane) * 8;
#pragma unroll
  for (int e = 0; e < 8; ++e) {
    float w = src[e];
    unsigned short h = bf_hi(w);
    whi[dst + e] = h;
    wlo[dst + e] = bf_hi(w - bf_f(h));
  }
}

__global__ void pack_bias(const float* __restrict__ bi1, const float* __restrict__ bh1,
                          const float* __restrict__ bi2, const float* __restrict__ bh2,
                          const float* __restrict__ bi3, const float* __restrict__ bh3,
                          float* __restrict__ bias) {
  int gid = blockIdx.x * 256 + threadIdx.x;
  if (gid >= 6144) return;
  int l = gid >> 11, r = gid & 2047;
  const float* bi = (l == 0) ? bi1 : (l == 1) ? bi2 : bi3;
  const float* bh = (l == 0) ? bh1 : (l == 1) ? bh2 : bh3;
  bias[gid] = bi[r] + bh[r];
}

// Two-level barrier, ALL RELAXED (no acquire-inv / release-wbl2 -> L2 stays
// warm with weights). Safe because: (1) __syncthreads on entry drains
// vmcnt(0), so this block's system-scope h stores are globally visible
// before arrival; (2) all cross-block data moves via system-scope atomics
// (MALL-coherent, never cached in L1/L2); (3) the trailing __syncthreads is
// a compiler+HW barrier ordering subsequent loads after the epoch observation.
__device__ __forceinline__ void gridbar(unsigned* bar, unsigned idx, int xcd) {
  __syncthreads();
  if (threadIdx.x == 0) {
    asm volatile("" ::: "memory");
    unsigned* xc   = bar + xcd * 32;
    unsigned* root = bar + 256;
    unsigned* ep   = bar + 288;
    unsigned o = __hip_atomic_fetch_add(xc, 1u, __ATOMIC_RELAXED, __HIP_MEMORY_SCOPE_AGENT);
    if (o == idx * 32u - 1u) {
      unsigned r = __hip_atomic_fetch_add(root, 1u, __ATOMIC_RELAXED, __HIP_MEMORY_SCOPE_AGENT);
      if (r == idx * 8u - 1u)
        __hip_atomic_store(ep, idx, __ATOMIC_RELAXED, __HIP_MEMORY_SCOPE_AGENT);
    }
    while (__hip_atomic_load(ep, __ATOMIC_RELAXED, __HIP_MEMORY_SCOPE_AGENT) < idx)
      __builtin_amdgcn_s_sleep(1);
    asm volatile("" ::: "memory");
  }
  __syncthreads();
}

// Persistent fused LSTM: 256 blocks x 1024 threads (16 waves = 4/SIMD).
// Block = (b-tile 32, j-tile 8); layer l at t = p - l (3-stage pipeline).
// Wave w: bsub=w&1 (16 b-rows), kq=w>>1 (K eighth); each wave computes BOTH
// 16-col n-subtiles so the uncached A-stream is read exactly once per block.
// A = 2-split bf16 (hi/lo) via system-scope loads (MALL); B = 2-split from
// L2-cached packed weights; 4 MFMAs chained into one acc per subtile.
__global__ __launch_bounds__(1024, 4) void lstm_persist(
    const float* __restrict__ embed,
    const unsigned short* __restrict__ whi,
    const unsigned short* __restrict__ wlo,
    const float* __restrict__ bias,
    unsigned short* __restrict__ hh,
    unsigned short* __restrict__ hl,
    float* __restrict__ h3f,
    unsigned* __restrict__ bar)
{
  const int bid = blockIdx.x;
  const int xcd = bid & 7;
  const int idx = bid >> 3;           // 0..31 within XCD
  const int jt  = xcd * 8 + (idx & 7);
  const int bt  = idx >> 3;           // 0..3
  const int j0  = jt * 8;
  const int b0  = bt * 32;
  const int tid = (int)threadIdx.x;
  const int lane = tid & 63;
  const int w = tid >> 6;             // 0..15
  const int bsub = w & 1, kq = w >> 1;            // kq 0..7

  __shared__ float pre[2][8][32][36];   // [parity][kq][brow][gatecol]
  __shared__ float sbias[3][32];

  if (tid < 96) {
    int l = tid >> 5, n = tid & 31;
    sbias[l][n] = bias[l * 2048 + (n >> 3) * 512 + j0 + (n & 7)];
  }
  // zero h state via SYSTEM stores (plain stores would sit dirty in this
  // XCD's L2, invisible to other XCDs' sc-reads)
  for (int i = bid * 1024 + tid; i < (3 * 2 * Bn * Hn) / 4; i += NB * 1024) {
    __hip_atomic_store((unsigned long long*)hh + i, 0ull, __ATOMIC_RELAXED, __HIP_MEMORY_SCOPE_SYSTEM);
    __hip_atomic_store((unsigned long long*)hl + i, 0ull, __ATOMIC_RELAXED, __HIP_MEMORY_SCOPE_SYSTEM);
  }

  float c0 = 0.f, c1 = 0.f, c2 = 0.f;   // cell state for (b0+bloc, j0+jl), tid<256
  unsigned bidx = 1;
  gridbar(bar, bidx++, xcd);

  const int arow = b0 + bsub * 16 + (lane & 15);   // A-frag b row
  const int kgrp = (lane >> 4) * 8;                // k-offset in 32-chunk
  const int bloc = (tid >> 3) & 31, jl = tid & 7;  // cell-update mapping (tid<256)

  for (int p = 0; p <= 1024; ++p) {
    const int rp = (p + 1) & 1, wp = p & 1;

#pragma unroll
    for (int l = 0; l < 3; ++l) {
      const int t = p - l;
      if (t >= 0 && t <= 1022) {
        const int NCH = (l == 0) ? 24 : 32;
        const int eighth = NCH >> 3;                 // 3 or 4
        const size_t wbase = (l == 0) ? 0u : ((l == 1) ? 1572864u : 3670016u);
        const unsigned short* wh0 = whi + wbase + ((size_t)(jt * 2 + 0) * NCH) * 512 + lane * 8;
        const unsigned short* wl0 = wlo + wbase + ((size_t)(jt * 2 + 0) * NCH) * 512 + lane * 8;
        const unsigned short* wh1 = whi + wbase + ((size_t)(jt * 2 + 1) * NCH) * 512 + lane * 8;
        const unsigned short* wl1 = wlo + wbase + ((size_t)(jt * 2 + 1) * NCH) * 512 + lane * 8;

        f32x4 acc0 = {0.f,0.f,0.f,0.f}, acc1 = {0.f,0.f,0.f,0.f};
        const int kc0 = kq * eighth;

#pragma unroll
        for (int i = 0; i < 4; ++i) {
          if (i >= eighth) break;                    // compile-time per l
          const int kc = kc0 + i;
          const int k0 = kc * 32 + kgrp;
          bf16x8 aH, aL;
          if (l == 0 && kc < 8) {                    // embed fp32 -> 2-split in-register
            const float* s = embed + ((size_t)arow * Tn + t) * INn + k0;
            const f32x4 x0 = *reinterpret_cast<const f32x4*>(s);
            const f32x4 x1 = *reinterpret_cast<const f32x4*>(s + 4);
            float xs[8] = {x0.x, x0.y, x0.z, x0.w, x1.x, x1.y, x1.z, x1.w};
#pragma unroll
            for (int e = 0; e < 8; ++e) {
              unsigned short h1 = bf_hi(xs[e]);
              aH[e] = (short)h1;
              aL[e] = (short)bf_hi(xs[e] - bf_f(h1));
            }
          } else {
            int srcl, off;
            if (l == 0)           { srcl = 0;     off = k0 - 256; }
            else if (k0 < 512)    { srcl = l - 1; off = k0;       }
            else                  { srcl = l;     off = k0 - 512; }
            const size_t ho = ((size_t)(srcl * 2 + rp) * Bn + arow) * Hn + off;
            aH = ld16sys(hh + ho);
            aL = ld16sys(hl + ho);
          }
          const bf16x8 bH0 = *reinterpret_cast<const bf16x8*>(wh0 + (size_t)kc * 512);
          const bf16x8 bL0 = *reinterpret_cast<const bf16x8*>(wl0 + (size_t)kc * 512);
          const bf16x8 bH1 = *reinterpret_cast<const bf16x8*>(wh1 + (size_t)kc * 512);
          const bf16x8 bL1 = *reinterpret_cast<const bf16x8*>(wl1 + (size_t)kc * 512);
          acc0 = __builtin_amdgcn_mfma_f32_16x16x32_bf16(aH, bH0, acc0, 0, 0, 0);
          acc0 = __builtin_amdgcn_mfma_f32_16x16x32_bf16(aL, bH0, acc0, 0, 0, 0);
          acc0 = __builtin_amdgcn_mfma_f32_16x16x32_bf16(aH, bL0, acc0, 0, 0, 0);
          acc0 = __builtin_amdgcn_mfma_f32_16x16x32_bf16(aL, bL0, acc0, 0, 0, 0);
          acc1 = __builtin_amdgcn_mfma_f32_16x16x32_bf16(aH, bH1, acc1, 0, 0, 0);
          acc1 = __builtin_amdgcn_mfma_f32_16x16x32_bf16(aL, bH1, acc1, 0, 0, 0);
          acc1 = __builtin_amdgcn_mfma_f32_16x16x32_bf16(aH, bL1, acc1, 0, 0, 0);
          acc1 = __builtin_amdgcn_mfma_f32_16x16x32_bf16(aL, bL1, acc1, 0, 0, 0);
        }

        const int pb = l & 1;  // l0/l2 share plane 0: separated by l1's __syncthreads
        {
          const int prow = bsub * 16 + ((lane >> 4) << 2);
          const int pc = lane & 15;
#pragma unroll
          for (int r = 0; r < 4; ++r) {
            pre[pb][kq][prow + r][pc]      = acc0[r];
            pre[pb][kq][prow + r][16 + pc] = acc1[r];
          }
        }
        __syncthreads();
        if (tid < 256) {
          float g0 = sbias[l][jl],      g1 = sbias[l][8 + jl];
          float g2 = sbias[l][16 + jl], g3 = sbias[l][24 + jl];
#pragma unroll
          for (int q = 0; q < 8; ++q) {
            g0 += pre[pb][q][bloc][jl];
            g1 += pre[pb][q][bloc][8 + jl];
            g2 += pre[pb][q][bloc][16 + jl];
            g3 += pre[pb][q][bloc][24 + jl];
          }
          const float ig = sigm(g0), fg = sigm(g1), gg = tanhf(g2), og = sigm(g3);
          float& c = (l == 0) ? c0 : ((l == 1) ? c1 : c2);
          c = fg * c + ig * gg;
          const float hv = og * tanhf(c);
          const unsigned short h1 = bf_hi(hv);
          const size_t ho = ((size_t)(l * 2 + wp) * Bn + (b0 + bloc)) * Hn + (j0 + jl);
          st2sys(hh + ho, h1);
          st2sys(hl + ho, bf_hi(hv - bf_f(h1)));
          if (l == 2 && t == 1022)
            h3f[(size_t)(b0 + bloc) * Hn + (j0 + jl)] = hv;
        }
      }
    }
    gridbar(bar, bidx++, xcd);
  }
}

// FC epilogue: out2[b][o] = h3_final[b,:] . fc_w[o,:] + fc_b[o]
__global__ void fc_kernel(const float* __restrict__ h3f, const float* __restrict__ fcw,
                          const float* __restrict__ fcb, float* __restrict__ out) {
  const int gid = blockIdx.x * 256 + (int)threadIdx.x;
  if (gid >= Bn * INn) return;
  const int b = gid >> 8, o = gid & 255;
  const float* hr = h3f + (size_t)b * Hn;
  const float* wr = fcw + (size_t)o * Hn;
  float acc = fcb[o];
#pragma unroll 4
  for (int k = 0; k < Hn; k += 4) {
    const float4 hv = *reinterpret_cast<const float4*>(hr + k);
    const float4 wv = *reinterpret_cast<const float4*>(wr + k);
    acc = fmaf(hv.x, wv.x, acc); acc = fmaf(hv.y, wv.y, acc);
    acc = fmaf(hv.z, wv.z, acc); acc = fmaf(hv.w, wv.w, acc);
  }
  out[(size_t)Bn * Tn * INn + gid] = acc;
}

extern "C" void kernel_launch(void* const* d_in, const int* in_sizes, int n_in,
                              void* d_out, int out_size, void* d_ws, size_t ws_size,
                              hipStream_t stream) {
  const float* embed = (const float*)d_in[0];
  const float* wih1  = (const float*)d_in[1];
  const float* whh1  = (const float*)d_in[2];
  const float* bih1  = (const float*)d_in[3];
  const float* bhh1  = (const float*)d_in[4];
  const float* wih2  = (const float*)d_in[5];
  const float* whh2  = (const float*)d_in[6];
  const float* bih2  = (const float*)d_in[7];
  const float* bhh2  = (const float*)d_in[8];
  const float* wih3  = (const float*)d_in[9];
  const float* whh3  = (const float*)d_in[10];
  const float* bih3  = (const float*)d_in[11];
  const float* bhh3  = (const float*)d_in[12];
  const float* fcw   = (const float*)d_in[13];
  const float* fcb   = (const float*)d_in[14];
  float* outp = (float*)d_out;

  char* ws = (char*)d_ws;
  unsigned short* whi = (unsigned short*)(ws + WHI_OFF);
  unsigned short* wlo = (unsigned short*)(ws + WLO_OFF);
  float* bias         = (float*)(ws + BIAS_OFF);
  unsigned short* hh  = (unsigned short*)(ws + HH_OFF);
  unsigned short* hl  = (unsigned short*)(ws + HL_OFF);
  float* h3f          = (float*)(ws + H3F_OFF);
  unsigned* bar       = (unsigned*)(ws + CNT_OFF);

  // Output 0: embed passthrough (128 MB d2d)
  hipMemcpyAsync(d_out, d_in[0], (size_t)Bn * Tn * INn * sizeof(float),
                 hipMemcpyDeviceToDevice, stream);
  // barrier counters must start at 0 every launch
  hipMemsetAsync(bar, 0, 8192, stream);

  pack_weights<<<2816, 256, 0, stream>>>(wih1, whh1, wih2, whh2, wih3, whh3, whi, wlo);
  pack_bias<<<24, 256, 0, stream>>>(bih1, bhh1, bih2, bhh2, bih3, bhh3, bias);

  void* args[] = { (void*)&embed, (void*)&whi, (void*)&wlo, (void*)&bias,
                   (void*)&hh, (void*)&hl, (void*)&h3f, (void*)&bar };
  dim3 grid(NB), block(1024);
  hipLaunchCooperativeKernel((const void*)lstm_persist, grid, block, args, 0, stream);

  fc_kernel<<<128, 256, 0, stream>>>(h3f, fcw, fcb, outp);
}